// Round 15
// baseline (155.055 us; speedup 1.0000x reference)
//
#include <hip/hip_runtime.h>
#include <hip/hip_bf16.h>
#include <hip/hip_fp8.h>
#include <stdint.h>

#define B_ROWS 1024
#define DIM    512
#define C_CLS  100000
#define C_PAD  100352          // 8 XCDs * 98 ntiles * 128
#define NT     784             // C_PAD / 128
#define NT_PER_XCD 98
#define MT     8               // B_ROWS / 128
#define NPAD   (C_PAD - C_CLS) // 352 pad cols, logit 0

using f32x4 = __attribute__((ext_vector_type(4))) float;
using i32x4 = __attribute__((ext_vector_type(4))) int;
using i32x8 = __attribute__((ext_vector_type(8))) int;

#define AS1(p) ((const __attribute__((address_space(1))) uint32_t*)(p))
#define AS3(p) ((__attribute__((address_space(3))) uint32_t*)(p))
#define SBAR()   __builtin_amdgcn_s_barrier()
#define SCHED0() __builtin_amdgcn_sched_barrier(0)
#define LGKM0()  asm volatile("s_waitcnt lgkmcnt(0)" ::: "memory")
#define VMCNT0() asm volatile("s_waitcnt vmcnt(0)" ::: "memory")

static __device__ __forceinline__ uint32_t f2fp8(float f) {
    __hip_fp8_e4m3 q(f);
    return (uint32_t)q.__x;
}
static __device__ __forceinline__ float fp82f(uint32_t b) {
    __hip_fp8_e4m3 h;
    h.__x = (__hip_fp8_storage_t)b;
    return (float)h;
}

// ---------- pass 1: per-row L2 normalize (one wave per row), f32 -> fp8 e4m3; pad rows zeroed
__global__ __launch_bounds__(256) void normalize_rows(
    const float* __restrict__ src, uint8_t* __restrict__ dst, int nvalid, int ntotal)
{
    const int row  = blockIdx.x * 4 + (threadIdx.x >> 6);
    const int lane = threadIdx.x & 63;
    if (row >= ntotal) return;
    uint2* d2 = reinterpret_cast<uint2*>(dst + (size_t)row * DIM);    // 8 B per lane
    if (row >= nvalid) { d2[lane] = make_uint2(0u, 0u); return; }
    const float4* s4 = reinterpret_cast<const float4*>(src + (size_t)row * DIM);
    const float4 a = s4[lane * 2], b = s4[lane * 2 + 1];
    float ss = a.x*a.x + a.y*a.y + a.z*a.z + a.w*a.w
             + b.x*b.x + b.y*b.y + b.z*b.z + b.w*b.w;
    #pragma unroll
    for (int k = 1; k < 64; k <<= 1) ss += __shfl_xor(ss, k);
    const float inv = 1.0f / fmaxf(sqrtf(ss), 1e-12f);
    uint2 o;
    o.x = f2fp8(a.x*inv) | (f2fp8(a.y*inv) << 8) | (f2fp8(a.z*inv) << 16) | (f2fp8(a.w*inv) << 24);
    o.y = f2fp8(b.x*inv) | (f2fp8(b.y*inv) << 8) | (f2fp8(b.z*inv) << 16) | (f2fp8(b.w*inv) << 24);
    d2[lane] = o;
}

// ---------- pass 2: 128x128 MX-fp8 MFMA (K=128, unit scales), 2-deep software pipeline:
//            LDS dbuf + DOUBLE fragment sets (fits: acc=64) -> reads drain under MFMA,
//            stage flies across iterations. Full unroll for static frag indexing.
__global__ __launch_bounds__(256, 2) void gemm_lse(
    const uint8_t* __restrict__ A,    // [B_ROWS][DIM]  fp8
    const uint8_t* __restrict__ W,    // [C_PAD][DIM]   fp8 (pad rows zero)
    float* __restrict__ ps)           // [NT][B_ROWS]
{
    // [buf][region: 0=A, 1=B][128 rows * 128 k fp8], 64 KiB double buffer
    __shared__ __align__(16) uint8_t lds[2][2][128 * 128];

    const int tid  = threadIdx.x;
    const int lane = tid & 63;
    const int wid  = tid >> 6;       // 4 waves, 2x2: each owns 64x64
    const int wm   = wid >> 1;
    const int wn   = wid & 1;

    const int b     = blockIdx.x;
    const int xcd   = b & 7;
    const int j     = b >> 3;        // 0..783 within XCD
    const int ntile = xcd * NT_PER_XCD + (j >> 3);
    const int mtile = j & 7;

    const uint8_t* Abase = A + (size_t)mtile * 128 * DIM;
    const uint8_t* Bbase = W + (size_t)ntile * 128 * DIM;

    // staging: per region 1024 16B units (row = u>>3, 16B-sub = u&7); source sub
    // pre-swizzled by row&7 (both-sides XOR, 16B granularity -> contiguous source).
    auto stage = [&](int kt, int buf) {
        #pragma unroll
        for (int p = 0; p < 4; ++p) {
            const int u   = tid + p * 256;
            const int row = u >> 3;
            const int sub = (u & 7) ^ (row & 7);
            const uint8_t* As = Abase + (size_t)row * DIM + kt * 128 + sub * 16;
            const uint8_t* Bs = Bbase + (size_t)row * DIM + kt * 128 + sub * 16;
            __builtin_amdgcn_global_load_lds(AS1(As), AS3(&lds[buf][0][u * 16]), 16, 0, 0);
            __builtin_amdgcn_global_load_lds(AS1(Bs), AS3(&lds[buf][1][u * 16]), 16, 0, 0);
        }
    };

    const int l15 = lane & 15;
    const int uhi = lane >> 4;       // k-quarter: lane holds k = uhi*32 .. +32

    i32x8 aF[2][4], bF[2][4];        // double fragment sets (set i <-> tile parity i)
    f32x4 acc[4][4] = {};

    auto ldfrag = [&](int buf, int reg, int row) -> i32x8 {
        const int swz = row & 7;
        const uint8_t* base = &lds[buf][reg][0];
        const i32x4 lo = *reinterpret_cast<const i32x4*>(base + row * 128 + (((uhi << 1) | 0) ^ swz) * 16);
        const i32x4 hi = *reinterpret_cast<const i32x4*>(base + row * 128 + (((uhi << 1) | 1) ^ swz) * 16);
        i32x8 r;
        r[0] = lo[0]; r[1] = lo[1]; r[2] = lo[2]; r[3] = lo[3];
        r[4] = hi[0]; r[5] = hi[1]; r[6] = hi[2]; r[7] = hi[3];
        return r;
    };

    // prologue: tile0 -> buf0 -> frag set 0; tile1 staged to buf1 in flight
    stage(0, 0);
    VMCNT0(); SBAR();
    #pragma unroll
    for (int mi = 0; mi < 4; ++mi) aF[0][mi] = ldfrag(0, 0, wm * 64 + mi * 16 + l15);
    #pragma unroll
    for (int ni = 0; ni < 4; ++ni) bF[0][ni] = ldfrag(0, 1, wn * 64 + ni * 16 + l15);
    stage(1, 1);

    #pragma unroll
    for (int kt = 0; kt < 4; ++kt) {
        const int cur = kt & 1, nxt = cur ^ 1;
        LGKM0(); SCHED0();            // my ds_reads retired -> cross-wave WAR safe
        VMCNT0();                     // stage(kt+1) landed (issued ~1 kt ago; ~free)
        SBAR();
        if (kt < 3) {                 // reads for tile kt+1 drain under MFMA(kt)
            #pragma unroll
            for (int mi = 0; mi < 4; ++mi) aF[nxt][mi] = ldfrag(nxt, 0, wm * 64 + mi * 16 + l15);
            #pragma unroll
            for (int ni = 0; ni < 4; ++ni) bF[nxt][ni] = ldfrag(nxt, 1, wn * 64 + ni * 16 + l15);
        }
        if (kt < 2) stage(kt + 2, cur);  // VMEM in flight across this and next iter
        #pragma unroll
        for (int mi = 0; mi < 4; ++mi)
            #pragma unroll
            for (int ni = 0; ni < 4; ++ni)
                acc[mi][ni] = __builtin_amdgcn_mfma_scale_f32_16x16x128_f8f6f4(
                    aF[cur][mi], bF[cur][ni], acc[mi][ni], 0, 0, 0, 127, 0, 127);
    }

    // epilogue: logits = 64*cos in [-64,64]; fixed shift 64 -> sum exp(logit-64)
    __syncthreads();                               // full drain; reuse LDS as red buffer
    float* red = reinterpret_cast<float*>(&lds[0][0][0]);   // [128 rows][2 wn]
    #pragma unroll
    for (int mi = 0; mi < 4; ++mi) {
        #pragma unroll
        for (int r = 0; r < 4; ++r) {
            float s = __expf(fmaf(acc[mi][0][r], 64.0f, -64.0f))
                    + __expf(fmaf(acc[mi][1][r], 64.0f, -64.0f))
                    + __expf(fmaf(acc[mi][2][r], 64.0f, -64.0f))
                    + __expf(fmaf(acc[mi][3][r], 64.0f, -64.0f));
            #pragma unroll
            for (int k = 1; k < 16; k <<= 1) s += __shfl_xor(s, k);
            if (l15 == 0) red[(wm * 64 + mi * 16 + uhi * 4 + r) * 2 + wn] = s;
        }
    }
    __syncthreads();
    if (tid < 128)
        ps[(size_t)ntile * B_ROWS + mtile * 128 + tid] = red[tid * 2] + red[tid * 2 + 1];
}

// ---------- pass 3: per-row sum of partials + exact margin/pad correction
__global__ __launch_bounds__(256) void finalize(
    const float* __restrict__ ps,
    const uint8_t* __restrict__ fb, const uint8_t* __restrict__ wb,
    const int* __restrict__ labels, float* __restrict__ row_loss)
{
    const int row = blockIdx.x;
    const int t   = threadIdx.x;      // 256
    const int lab = labels[row];

    // target logit from the SAME fp8 values the GEMM consumed (consistent cancellation)
    const uint8_t* frow = fb + (size_t)row * DIM;
    const uint8_t* wrow = wb + (size_t)lab * DIM;
    uint32_t fa = *reinterpret_cast<const uint16_t*>(frow + 2 * t);
    uint32_t wa = *reinterpret_cast<const uint16_t*>(wrow + 2 * t);
    float d = fp82f(fa & 0xffu) * fp82f(wa & 0xffu)
            + fp82f(fa >> 8)    * fp82f(wa >> 8);
    #pragma unroll
    for (int k = 1; k < 64; k <<= 1) d += __shfl_xor(d, k);

    float s = 0.0f;
    for (int i = t; i < NT; i += 256) s += ps[(size_t)i * B_ROWS + row];
    #pragma unroll
    for (int k = 1; k < 64; k <<= 1) s += __shfl_xor(s, k);

    __shared__ float sd[4], ssm[4];
    if ((t & 63) == 0) { sd[t >> 6] = d; ssm[t >> 6] = s; }
    __syncthreads();
    if (t == 0) {
        const float dt = sd[0] + sd[1] + sd[2] + sd[3];
        float S = ssm[0] + ssm[1] + ssm[2] + ssm[3];
        const float lt = 64.0f * dt;
        // swap unmargined target term for margined one; remove pad columns (logit 0)
        S += expf(lt - 96.0f) - expf(lt - 64.0f) - (float)NPAD * expf(-64.0f);
        row_loss[row] = 64.0f + logf(S) - (lt - 32.0f);
    }
}

// ---------- pass 4: mean over rows
__global__ __launch_bounds__(256) void mean_k(const float* __restrict__ rl, float* __restrict__ out)
{
    const int t = threadIdx.x;
    float s = 0.0f;
    for (int i = t; i < B_ROWS; i += 256) s += rl[i];
    #pragma unroll
    for (int k = 1; k < 64; k <<= 1) s += __shfl_xor(s, k);
    __shared__ float r4[4];
    if ((t & 63) == 0) r4[t >> 6] = s;
    __syncthreads();
    if (t == 0) out[0] = (r4[0] + r4[1] + r4[2] + r4[3]) * (1.0f / B_ROWS);
}

extern "C" void kernel_launch(void* const* d_in, const int* in_sizes, int n_in,
                              void* d_out, int out_size, void* d_ws, size_t ws_size,
                              hipStream_t stream)
{
    const float* features = (const float*)d_in[0];
    const int*   labels   = (const int*)d_in[1];
    const float* weight   = (const float*)d_in[2];

    char* ws = (char*)d_ws;
    uint8_t* wb = (uint8_t*)ws;                                          // C_PAD * DIM fp8
    uint8_t* fb = (uint8_t*)(ws + (size_t)C_PAD * DIM);                  // B_ROWS * DIM fp8
    float*   psum = (float*)(ws + (size_t)C_PAD * DIM + (size_t)B_ROWS * DIM);
    float*   rl = psum + (size_t)NT * B_ROWS;

    normalize_rows<<<C_PAD / 4, 256, 0, stream>>>(weight, wb, C_CLS, C_PAD);
    normalize_rows<<<B_ROWS / 4, 256, 0, stream>>>(features, fb, B_ROWS, B_ROWS);
    gemm_lse<<<NT * MT, 256, 0, stream>>>(fb, wb, psum);
    finalize<<<B_ROWS, 256, 0, stream>>>(psum, fb, wb, labels, rl);
    mean_k<<<1, 256, 0, stream>>>(rl, (float*)d_out);
}

// Round 16
// 129.690 us; speedup vs baseline: 1.1956x; 1.1956x over previous
//
#include <hip/hip_runtime.h>
#include <hip/hip_bf16.h>
#include <hip/hip_fp8.h>
#include <stdint.h>

#define B_ROWS 1024
#define DIM    512
#define C_CLS  100000
#define C_PAD  100352          // 8 XCDs * 98 ntiles * 128
#define NT     784             // C_PAD / 128
#define NT_PER_XCD 98
#define MT     8               // B_ROWS / 128
#define NPAD   (C_PAD - C_CLS) // 352 pad cols, logit 0

using f32x4 = __attribute__((ext_vector_type(4))) float;
using i32x4 = __attribute__((ext_vector_type(4))) int;
using i32x8 = __attribute__((ext_vector_type(8))) int;

#define AS1(p) ((const __attribute__((address_space(1))) uint32_t*)(p))
#define AS3(p) ((__attribute__((address_space(3))) uint32_t*)(p))
#define SBAR()   __builtin_amdgcn_s_barrier()
#define SCHED0() __builtin_amdgcn_sched_barrier(0)
#define LGKM0()  asm volatile("s_waitcnt lgkmcnt(0)" ::: "memory")
#define VMCNT0() asm volatile("s_waitcnt vmcnt(0)" ::: "memory")

static __device__ __forceinline__ uint32_t f2fp8(float f) {
    __hip_fp8_e4m3 q(f);
    return (uint32_t)q.__x;
}
static __device__ __forceinline__ float fp82f(uint32_t b) {
    __hip_fp8_e4m3 h;
    h.__x = (__hip_fp8_storage_t)b;
    return (float)h;
}

// ---------- pass 1: per-row L2 normalize (one wave per row), f32 -> fp8 e4m3; pad rows zeroed
__global__ __launch_bounds__(256) void normalize_rows(
    const float* __restrict__ src, uint8_t* __restrict__ dst, int nvalid, int ntotal)
{
    const int row  = blockIdx.x * 4 + (threadIdx.x >> 6);
    const int lane = threadIdx.x & 63;
    if (row >= ntotal) return;
    uint2* d2 = reinterpret_cast<uint2*>(dst + (size_t)row * DIM);    // 8 B per lane
    if (row >= nvalid) { d2[lane] = make_uint2(0u, 0u); return; }
    const float4* s4 = reinterpret_cast<const float4*>(src + (size_t)row * DIM);
    const float4 a = s4[lane * 2], b = s4[lane * 2 + 1];
    float ss = a.x*a.x + a.y*a.y + a.z*a.z + a.w*a.w
             + b.x*b.x + b.y*b.y + b.z*b.z + b.w*b.w;
    #pragma unroll
    for (int k = 1; k < 64; k <<= 1) ss += __shfl_xor(ss, k);
    const float inv = 1.0f / fmaxf(sqrtf(ss), 1e-12f);
    uint2 o;
    o.x = f2fp8(a.x*inv) | (f2fp8(a.y*inv) << 8) | (f2fp8(a.z*inv) << 16) | (f2fp8(a.w*inv) << 24);
    o.y = f2fp8(b.x*inv) | (f2fp8(b.y*inv) << 8) | (f2fp8(b.z*inv) << 16) | (f2fp8(b.w*inv) << 24);
    d2[lane] = o;
}

// ---------- pass 2: 128x128 MX-fp8 MFMA (K=128, unit scales), m97 structure, 3 blocks/CU;
//            stage(kt+1) issued BEFORE the MFMAs (after LGKM0+SBAR read-retire fence) so
//            the VMEM flight is covered by the MFMA phase instead of fully exposed.
__global__ __launch_bounds__(256, 3) void gemm_lse(
    const uint8_t* __restrict__ A,    // [B_ROWS][DIM]  fp8
    const uint8_t* __restrict__ W,    // [C_PAD][DIM]   fp8 (pad rows zero)
    float* __restrict__ ps)           // [NT][B_ROWS]
{
    // [region: 0=A, 1=B][128 rows * 128 k fp8 = 16384 B], 32 KiB single buffer
    __shared__ __align__(16) uint8_t lds[2][128 * 128];

    const int tid  = threadIdx.x;
    const int lane = tid & 63;
    const int wid  = tid >> 6;       // 4 waves, 2x2: each owns 64x64
    const int wm   = wid >> 1;
    const int wn   = wid & 1;

    const int b     = blockIdx.x;
    const int xcd   = b & 7;
    const int j     = b >> 3;        // 0..783 within XCD
    const int ntile = xcd * NT_PER_XCD + (j >> 3);
    const int mtile = j & 7;

    const uint8_t* Abase = A + (size_t)mtile * 128 * DIM;
    const uint8_t* Bbase = W + (size_t)ntile * 128 * DIM;

    // staging: per region 1024 16B units (row = u>>3, 16B-sub = u&7); source sub
    // pre-swizzled by row&7 (both-sides XOR, 16B granularity -> contiguous source).
    auto stage = [&](int kt) {
        #pragma unroll
        for (int p = 0; p < 4; ++p) {
            const int u   = tid + p * 256;
            const int row = u >> 3;
            const int sub = (u & 7) ^ (row & 7);
            const uint8_t* As = Abase + (size_t)row * DIM + kt * 128 + sub * 16;
            const uint8_t* Bs = Bbase + (size_t)row * DIM + kt * 128 + sub * 16;
            __builtin_amdgcn_global_load_lds(AS1(As), AS3(&lds[0][u * 16]), 16, 0, 0);
            __builtin_amdgcn_global_load_lds(AS1(Bs), AS3(&lds[1][u * 16]), 16, 0, 0);
        }
    };

    const int l15 = lane & 15;
    const int uhi = lane >> 4;       // k-quarter: lane holds k = uhi*32 .. +32

    i32x8 aF[4], bF[4];
    f32x4 acc[4][4] = {};

    auto ldfrag = [&](const uint8_t* base, int row) -> i32x8 {
        const int swz = row & 7;
        const i32x4 lo = *reinterpret_cast<const i32x4*>(base + row * 128 + (((uhi << 1) | 0) ^ swz) * 16);
        const i32x4 hi = *reinterpret_cast<const i32x4*>(base + row * 128 + (((uhi << 1) | 1) ^ swz) * 16);
        i32x8 r;
        r[0] = lo[0]; r[1] = lo[1]; r[2] = lo[2]; r[3] = lo[3];
        r[4] = hi[0]; r[5] = hi[1]; r[6] = hi[2]; r[7] = hi[3];
        return r;
    };

    // prologue
    stage(0);

    #pragma unroll 1
    for (int kt = 0; kt < 4; ++kt) {
        VMCNT0(); SBAR();                 // tile kt landed for all waves
        #pragma unroll
        for (int mi = 0; mi < 4; ++mi) aF[mi] = ldfrag(&lds[0][0], wm * 64 + mi * 16 + l15);
        #pragma unroll
        for (int ni = 0; ni < 4; ++ni) bF[ni] = ldfrag(&lds[1][0], wn * 64 + ni * 16 + l15);
        LGKM0(); SCHED0(); SBAR();        // all waves' reads retired -> overwrite safe
        if (kt < 3) stage(kt + 1);        // VMEM flies under the MFMA phase below
        #pragma unroll
        for (int mi = 0; mi < 4; ++mi)
            #pragma unroll
            for (int ni = 0; ni < 4; ++ni)
                acc[mi][ni] = __builtin_amdgcn_mfma_scale_f32_16x16x128_f8f6f4(
                    aF[mi], bF[ni], acc[mi][ni], 0, 0, 0, 127, 0, 127);
    }

    // epilogue: logits = 64*cos in [-64,64]; fixed shift 64 -> sum exp(logit-64)
    __syncthreads();                               // full drain; reuse LDS as red buffer
    float* red = reinterpret_cast<float*>(&lds[0][0]);      // [128 rows][2 wn]
    #pragma unroll
    for (int mi = 0; mi < 4; ++mi) {
        #pragma unroll
        for (int r = 0; r < 4; ++r) {
            float s = __expf(fmaf(acc[mi][0][r], 64.0f, -64.0f))
                    + __expf(fmaf(acc[mi][1][r], 64.0f, -64.0f))
                    + __expf(fmaf(acc[mi][2][r], 64.0f, -64.0f))
                    + __expf(fmaf(acc[mi][3][r], 64.0f, -64.0f));
            #pragma unroll
            for (int k = 1; k < 16; k <<= 1) s += __shfl_xor(s, k);
            if (l15 == 0) red[(wm * 64 + mi * 16 + uhi * 4 + r) * 2 + wn] = s;
        }
    }
    __syncthreads();
    if (tid < 128)
        ps[(size_t)ntile * B_ROWS + mtile * 128 + tid] = red[tid * 2] + red[tid * 2 + 1];
}

// ---------- pass 3: per-row sum of partials + exact margin/pad correction
__global__ __launch_bounds__(256) void finalize(
    const float* __restrict__ ps,
    const uint8_t* __restrict__ fb, const uint8_t* __restrict__ wb,
    const int* __restrict__ labels, float* __restrict__ row_loss)
{
    const int row = blockIdx.x;
    const int t   = threadIdx.x;      // 256
    const int lab = labels[row];

    // target logit from the SAME fp8 values the GEMM consumed (consistent cancellation)
    const uint8_t* frow = fb + (size_t)row * DIM;
    const uint8_t* wrow = wb + (size_t)lab * DIM;
    uint32_t fa = *reinterpret_cast<const uint16_t*>(frow + 2 * t);
    uint32_t wa = *reinterpret_cast<const uint16_t*>(wrow + 2 * t);
    float d = fp82f(fa & 0xffu) * fp82f(wa & 0xffu)
            + fp82f(fa >> 8)    * fp82f(wa >> 8);
    #pragma unroll
    for (int k = 1; k < 64; k <<= 1) d += __shfl_xor(d, k);

    float s = 0.0f;
    for (int i = t; i < NT; i += 256) s += ps[(size_t)i * B_ROWS + row];
    #pragma unroll
    for (int k = 1; k < 64; k <<= 1) s += __shfl_xor(s, k);

    __shared__ float sd[4], ssm[4];
    if ((t & 63) == 0) { sd[t >> 6] = d; ssm[t >> 6] = s; }
    __syncthreads();
    if (t == 0) {
        const float dt = sd[0] + sd[1] + sd[2] + sd[3];
        float S = ssm[0] + ssm[1] + ssm[2] + ssm[3];
        const float lt = 64.0f * dt;
        // swap unmargined target term for margined one; remove pad columns (logit 0)
        S += expf(lt - 96.0f) - expf(lt - 64.0f) - (float)NPAD * expf(-64.0f);
        row_loss[row] = 64.0f + logf(S) - (lt - 32.0f);
    }
}

// ---------- pass 4: mean over rows
__global__ __launch_bounds__(256) void mean_k(const float* __restrict__ rl, float* __restrict__ out)
{
    const int t = threadIdx.x;
    float s = 0.0f;
    for (int i = t; i < B_ROWS; i += 256) s += rl[i];
    #pragma unroll
    for (int k = 1; k < 64; k <<= 1) s += __shfl_xor(s, k);
    __shared__ float r4[4];
    if ((t & 63) == 0) r4[t >> 6] = s;
    __syncthreads();
    if (t == 0) out[0] = (r4[0] + r4[1] + r4[2] + r4[3]) * (1.0f / B_ROWS);
}

extern "C" void kernel_launch(void* const* d_in, const int* in_sizes, int n_in,
                              void* d_out, int out_size, void* d_ws, size_t ws_size,
                              hipStream_t stream)
{
    const float* features = (const float*)d_in[0];
    const int*   labels   = (const int*)d_in[1];
    const float* weight   = (const float*)d_in[2];

    char* ws = (char*)d_ws;
    uint8_t* wb = (uint8_t*)ws;                                          // C_PAD * DIM fp8
    uint8_t* fb = (uint8_t*)(ws + (size_t)C_PAD * DIM);                  // B_ROWS * DIM fp8
    float*   psum = (float*)(ws + (size_t)C_PAD * DIM + (size_t)B_ROWS * DIM);
    float*   rl = psum + (size_t)NT * B_ROWS;

    normalize_rows<<<C_PAD / 4, 256, 0, stream>>>(weight, wb, C_CLS, C_PAD);
    normalize_rows<<<B_ROWS / 4, 256, 0, stream>>>(features, fb, B_ROWS, B_ROWS);
    gemm_lse<<<NT * MT, 256, 0, stream>>>(fb, wb, psum);
    finalize<<<B_ROWS, 256, 0, stream>>>(psum, fb, wb, labels, rl);
    mean_k<<<1, 256, 0, stream>>>(rl, (float*)d_out);
}